// Round 6
// baseline (142.353 us; speedup 1.0000x reference)
//
#include <hip/hip_runtime.h>
#include <math.h>

// y[b,f,t] = | x[t] - C_f*w_f * S[t] |,  S[t] = sum_{j=0}^{497} a^j x[t-1-j] (edge-padded)
//
// R5 = R4 with the nontemporal-store type fixed (native ext_vector_type, not
// HIP_vector_type). R4: hoist per-f constant math (doubles, powi) into a
// 1-block setup kernel writing d_ws; main kernel uses L1-resident tables;
// warm-up S via the same DPP weighted scan (readlane 63); NT output stores.

constexpr int T     = 8000;
constexpr int F     = 64;
constexpr int B     = 32;
constexpr int KM1   = 498;
constexpr int CHUNK = 512;                       // samples per wave (8/lane)
constexpr int CPR   = (T + CHUNK - 1) / CHUNK;   // 16 chunks per row (last = 320)

typedef float nfloat4 __attribute__((ext_vector_type(4)));

#define DPP_F(x, ctrl, rm) \
  __builtin_bit_cast(float, __builtin_amdgcn_update_dpp(0, __builtin_bit_cast(int, (x)), (ctrl), (rm), 0xf, false))

__device__ __forceinline__ double dpow(double b, int e) {
    double r = 1.0, p = b;
    while (e) { if (e & 1) r *= p; p *= p; e >>= 1; }
    return r;
}

// ---- setup: per-f constants + power table into d_ws ----
// layout: cons[f][16] floats (9 used), then tbl[f][64] floats
__global__ void willmore_setup(const float* __restrict__ a, const float* __restrict__ w,
                               float* __restrict__ cons, float* __restrict__ tbl)
{
    const int tid = threadIdx.x;
    if (tid < F) {
        const double ad     = (double)a[tid];
        const double a498d  = dpow(ad, KM1);
        const double sumgeo = (1.0 - a498d) / (1.0 - ad);
        const double r      = dpow(ad, 8);
        float* c = cons + tid * 16;
        c[0] = (float)ad;                       // af
        c[1] = (float)(-a498d);                 // na498
        c[2] = (float)(1.0 / sumgeo) * w[tid];  // g = C*w
        c[3] = (float)r;                        // r^1
        c[4] = (float)(r * r);                  // r^2
        c[5] = (float)dpow(r, 4);               // r^4
        c[6] = (float)dpow(r, 8);               // r^8
        c[7] = (float)(1.0 / r);                // r^-1
        c[8] = (float)sumgeo;
    }
    for (int i = tid; i < F * 64; i += 256) {
        const int f = i >> 6, k = i & 63;
        tbl[i] = (float)dpow((double)a[f], 8 * k);
    }
}

__global__ __launch_bounds__(256) void willmore_scan_kernel(
    const float* __restrict__ x, const float* __restrict__ cons,
    const float* __restrict__ tbl, float* __restrict__ out)
{
    const int wid   = blockIdx.x * 4 + (threadIdx.x >> 6);
    const int lane  = threadIdx.x & 63;
    const int row   = wid >> 4;          // b*F + f
    const int chunk = wid & (CPR - 1);
    const int f     = row % F;

    const float* xr   = x   + (size_t)row * T;
    float*       orow = out + (size_t)row * T;

    // ---- constants from ws (L1/L2-resident) ----
    const float* c = cons + f * 16;
    const float4 c0 = *(const float4*)(c);      // af, na498, g, r1
    const float4 c1 = *(const float4*)(c + 4);  // r2, r4, r8, inv_r
    const float  af = c0.x, na498 = c0.y, g = c0.z, r1 = c0.w;
    const float  r2 = c1.x, r4 = c1.y, r8 = c1.z, inv_r = c1.w;
    const float  sumgeo = c[8];
    const float* tf = tbl + f * 64;
    const float  alane = tf[lane];               // a^(8*lane)
    const float  wA    = tf[(lane & 15) + 1];    // bcast15 weight
    const float  wB    = tf[(lane & 31) + 1];    // bcast31 weight

    const int t0   = chunk * CHUNK;
    const int tb_u = t0 + 8 * lane;          // unclamped output base
    const int tb   = min(tb_u, T - 8);       // clamp bites only in chunk 15

    // ---- issue all loads up front ----
    const float4 m0 = *(const float4*)(xr + tb);
    const float4 m1 = *(const float4*)(xr + tb + 4);

    float ws8[8];                            // warm-up window [t0-512, t0)
    float lv[8];                             // lag window x[tb-498 ..]
    const int lg = tb - KM1;
    if (chunk > 0) {
        const int wb = t0 - CHUNK + 8 * lane;
        const float4 w0 = *(const float4*)(xr + wb);
        const float4 w1 = *(const float4*)(xr + wb + 4);
        ws8[0]=w0.x; ws8[1]=w0.y; ws8[2]=w0.z; ws8[3]=w0.w;
        ws8[4]=w1.x; ws8[5]=w1.y; ws8[6]=w1.z; ws8[7]=w1.w;
        const float2 p0 = *(const float2*)(xr + lg);       // lg even -> 8B aligned
        const float2 p1 = *(const float2*)(xr + lg + 2);
        const float2 p2 = *(const float2*)(xr + lg + 4);
        const float2 p3 = *(const float2*)(xr + lg + 6);
        lv[0]=p0.x; lv[1]=p0.y; lv[2]=p1.x; lv[3]=p1.y;
        lv[4]=p2.x; lv[5]=p2.y; lv[6]=p3.x; lv[7]=p3.y;
    } else {
        #pragma unroll
        for (int i = 0; i < 8; ++i) lv[i] = xr[max(lg + i, 0)];
        #pragma unroll
        for (int i = 0; i < 8; ++i) ws8[i] = 0.0f;
    }

    // ---- warm-up S[t0]: Horner per lane, then weighted scan, take lane 63 ----
    // S[t0] = sum_l a^(8*(63-l)) * h_l with h_l = sum_i a^(7-i) x[t0-512+8l+i]
    float S;
    {
        // drop j>=498 (i.e. 8*lane+i < 14): only lanes 0,1
        #pragma unroll
        for (int i = 0; i < 8; ++i) { if (8 * lane + i < 14) ws8[i] = 0.0f; }
        float h = ws8[0];
        #pragma unroll
        for (int i = 1; i < 8; ++i) h = fmaf(h, af, ws8[i]);
        float Gw = h;
        Gw = fmaf(r1, DPP_F(Gw, 0x111, 0xf), Gw);
        Gw = fmaf(r2, DPP_F(Gw, 0x112, 0xf), Gw);
        Gw = fmaf(r4, DPP_F(Gw, 0x114, 0xf), Gw);
        Gw = fmaf(r8, DPP_F(Gw, 0x118, 0xf), Gw);
        Gw = fmaf(wA, DPP_F(Gw, 0x142, 0xa), Gw);
        Gw = fmaf(wB, DPP_F(Gw, 0x143, 0xc), Gw);
        S = __builtin_bit_cast(float,
                __builtin_amdgcn_readlane(__builtin_bit_cast(int, Gw), 63));
        if (chunk == 0) S = xr[0] * sumgeo;   // edge-padded closed form
    }

    // ---- main: u, lane aggregate, DPP weighted scan (ratio a^8) ----
    const float xv[8] = {m0.x, m0.y, m0.z, m0.w, m1.x, m1.y, m1.z, m1.w};
    float u[8];
    #pragma unroll
    for (int i = 0; i < 8; ++i) u[i] = fmaf(na498, lv[i], xv[i]);

    float q = u[0];
    #pragma unroll
    for (int i = 1; i < 8; ++i) q = fmaf(q, af, u[i]);

    float G = q;
    G = fmaf(r1, DPP_F(G, 0x111, 0xf), G);   // row_shr:1
    G = fmaf(r2, DPP_F(G, 0x112, 0xf), G);   // row_shr:2
    G = fmaf(r4, DPP_F(G, 0x114, 0xf), G);   // row_shr:4
    G = fmaf(r8, DPP_F(G, 0x118, 0xf), G);   // row_shr:8
    G = fmaf(wA, DPP_F(G, 0x142, 0xa), G);   // row_bcast15 -> rows 1,3
    G = fmaf(wB, DPP_F(G, 0x143, 0xc), G);   // row_bcast31 -> rows 2,3

    const float E = (G - q) * inv_r;         // exclusive prefix (exact 0 at lane 0)

    float s = fmaf(alane, S, E);             // S[t0 + 8*lane]
    nfloat4 y0, y1;
    #pragma unroll
    for (int i = 0; i < 4; ++i) {
        y0[i] = fabsf(fmaf(-g, s, xv[i]));
        s = fmaf(af, s, u[i]);
    }
    #pragma unroll
    for (int i = 0; i < 4; ++i) {
        y1[i] = fabsf(fmaf(-g, s, xv[4 + i]));
        s = fmaf(af, s, u[4 + i]);
    }

    if (tb_u <= T - 8) {
        __builtin_nontemporal_store(y0, (nfloat4*)(orow + tb));
        __builtin_nontemporal_store(y1, (nfloat4*)(orow + tb + 4));
    }
}

extern "C" void kernel_launch(void* const* d_in, const int* in_sizes, int n_in,
                              void* d_out, int out_size, void* d_ws, size_t ws_size,
                              hipStream_t stream) {
    const float* x = (const float*)d_in[0];
    const float* a = (const float*)d_in[1];
    const float* w = (const float*)d_in[2];
    float* out  = (float*)d_out;
    float* cons = (float*)d_ws;              // 64*16 floats
    float* tbl  = cons + F * 16;             // 64*64 floats (20.5 KB total)

    hipLaunchKernelGGL(willmore_setup, dim3(1), dim3(256), 0, stream, a, w, cons, tbl);
    const int blocks = B * F * CPR / 4;      // 8192 blocks x 4 waves
    hipLaunchKernelGGL(willmore_scan_kernel, dim3(blocks), dim3(256), 0, stream,
                       x, cons, tbl, out);
}